// Round 2
// baseline (346.755 us; speedup 1.0000x reference)
//
#include <hip/hip_runtime.h>

// WeightedSumSessEmbedding: out[s,:] = sum_{j: row_idx[j]==s} data[j] * emb[col_idx[j],:]
// row_idx is sorted. SINGLE fused kernel, no workspace use:
//   - each wave owns one session; segment bounds found by per-wave binary
//     search over row_idx (even lanes search lower_bound(sess), odd lanes
//     lower_bound(sess+1); 2 distinct probe addresses/iter, broadcast-coalesced;
//     row_idx is 3.3 MB -> probes are L2/L3 hits after warmup).
//   - 64 lanes = 4 nnz-chains x 16 float4-lanes (16B/lane, 256B/emb row).
//     Main loop: 16 nnz/iter, 4 independent col->emb gather chains in flight.
//   - tail: ONE masked pass of up to 16 nnz (4 independent chains).
//   - cross-chain reduce via shfl_xor(16),(32); out written exactly once,
//     nontemporal via native ext_vector_type (the builtin rejects
//     HIP_vector_type) -- no reuse, keep L2 for the emb gathers.
// Rationale: R0 rocprof showed ~1 GB fillBufferAligned dispatches (~152 us
// each; only d_ws is ~1 GB) inside the timed window while both user kernels
// ran <152 us. Eliminating all d_ws usage is the lever.

typedef float nfloat4 __attribute__((ext_vector_type(4)));

__global__ __launch_bounds__(256, 8) void wsum_fused_kernel(
    const int*    __restrict__ row_idx,  // [nnz], sorted
    const int*    __restrict__ col_idx,  // [nnz]
    const float*  __restrict__ data,     // [nnz]
    const float4* __restrict__ emb,      // [ITEMS_NUM, 16] as float4
    float4*       __restrict__ out,      // [num_sess, 16] as float4
    int num_sess, int nnz)
{
    const int wave = threadIdx.x >> 6;           // 0..3
    const int lane = threadIdx.x & 63;
    const int sess = (blockIdx.x << 2) + wave;   // one wave per session
    if (sess >= num_sess) return;

    // --- per-wave segment bounds: lower_bound(sess), lower_bound(sess+1) ---
    // All lanes run the search redundantly; lane parity picks the target.
    // Per probe iteration the wave touches only 2 distinct addresses.
    int target = sess + (lane & 1);
    int lo = 0, hi = nnz;
    while (lo < hi) {
        int mid = (lo + hi) >> 1;
        int v = row_idx[mid];
        if (v < target) lo = mid + 1; else hi = mid;
    }
    const int start = __shfl(lo, 0, 64);
    const int end   = __shfl(lo, 1, 64);

    const int r = lane >> 4;   // nnz chain within group-of-4
    const int c = lane & 15;   // float4 slot within the 64-float emb row

    float4 acc = make_float4(0.f, 0.f, 0.f, 0.f);

    int j0 = start;
    // 16 nnz per iteration: 4 independent gather chains in flight per lane
    for (; j0 + 16 <= end; j0 += 16) {
        int   c0 = col_idx[j0 + 0  + r];
        int   c1 = col_idx[j0 + 4  + r];
        int   c2 = col_idx[j0 + 8  + r];
        int   c3 = col_idx[j0 + 12 + r];
        float w0 = data[j0 + 0  + r];
        float w1 = data[j0 + 4  + r];
        float w2 = data[j0 + 8  + r];
        float w3 = data[j0 + 12 + r];
        float4 e0 = emb[((size_t)c0 << 4) + c];
        float4 e1 = emb[((size_t)c1 << 4) + c];
        float4 e2 = emb[((size_t)c2 << 4) + c];
        float4 e3 = emb[((size_t)c3 << 4) + c];
        acc.x += w0 * e0.x + w1 * e1.x + w2 * e2.x + w3 * e3.x;
        acc.y += w0 * e0.y + w1 * e1.y + w2 * e2.y + w3 * e3.y;
        acc.z += w0 * e0.z + w1 * e1.z + w2 * e2.z + w3 * e3.z;
        acc.w += w0 * e0.w + w1 * e1.w + w2 * e2.w + w3 * e3.w;
    }
    // tail: single masked pass of up to 16 nnz, 4 independent chains
    if (j0 < end) {
        #pragma unroll
        for (int k = 0; k < 4; ++k) {
            int   j     = j0 + (k << 2) + r;
            bool  valid = (j < end);
            int   col   = valid ? col_idx[j] : 0;
            float w     = valid ? data[j]    : 0.f;
            float4 e = emb[((size_t)col << 4) + c];
            acc.x += w * e.x;
            acc.y += w * e.y;
            acc.z += w * e.z;
            acc.w += w * e.w;
        }
    }

    // reduce the 4 chains (lanes differing in bits 4,5 hold the same dims)
    acc.x += __shfl_xor(acc.x, 16, 64);
    acc.y += __shfl_xor(acc.y, 16, 64);
    acc.z += __shfl_xor(acc.z, 16, 64);
    acc.w += __shfl_xor(acc.w, 16, 64);
    acc.x += __shfl_xor(acc.x, 32, 64);
    acc.y += __shfl_xor(acc.y, 32, 64);
    acc.z += __shfl_xor(acc.z, 32, 64);
    acc.w += __shfl_xor(acc.w, 32, 64);

    if (r == 0) {
        nfloat4 v = { acc.x, acc.y, acc.z, acc.w };
        __builtin_nontemporal_store(
            v, (nfloat4*)&out[((size_t)sess << 4) + c]);
    }
}

extern "C" void kernel_launch(void* const* d_in, const int* in_sizes, int n_in,
                              void* d_out, int out_size, void* d_ws, size_t ws_size,
                              hipStream_t stream) {
    const int*   row_idx = (const int*)  d_in[0];
    const int*   col_idx = (const int*)  d_in[1];
    const float* data    = (const float*)d_in[2];
    const float* emb     = (const float*)d_in[4];

    const int nnz      = in_sizes[0];
    const int num_sess = out_size / 64;   // EMB_DIM = 64

    (void)d_ws; (void)ws_size;            // workspace intentionally unused

    const int blocks = (num_sess + 3) / 4;   // 4 waves/block, 1 session/wave
    wsum_fused_kernel<<<blocks, 256, 0, stream>>>(
        row_idx, col_idx, data, (const float4*)emb, (float4*)d_out,
        num_sess, nnz);
}

// Round 3
// 338.750 us; speedup vs baseline: 1.0236x; 1.0236x over previous
//
#include <hip/hip_runtime.h>

// WeightedSumSessEmbedding: out[s,:] = sum_{j: row_idx[j]==s} data[j] * emb[col_idx[j],:]
// row_idx sorted. Two kernels (measured-best structure):
//   1) build_rowptr: CSR row_ptr[num_sess+1] in d_ws. Boundary detect; every
//      entry written exactly once -> deterministic, no init needed. One fully
//      parallel coalesced pass over row_idx (~1 us) -- beats the per-wave
//      binary search (20-step serial dependent-load chain, ~5-7 us prologue).
//      R2 PROVED the harness re-poisons d_ws (2x ~155us 1GB fills) whether or
//      not we use it, so using d_ws for row_ptr is free.
//   2) wsum: one wave per session; 64 lanes = 4 nnz-chains x 16 float4-lanes
//      (16B/lane, 256B/emb row). Main loop 16 nnz/iter -> 4 independent
//      col->emb gather chains in flight. Tail: ONE masked 16-wide pass
//      (4 chains; replaces up-to-4 serial dependent rounds). Cross-chain
//      reduce via shfl_xor(16),(32). Out written exactly once, nontemporal
//      (no reuse; keep L2/L3 for emb gathers -- emb is 256MB == L3 size).
// Timed-window anatomy (R0/R2 rocprof): ~310us unconditional ws-poison fills
// + ~26-37us kernels. Only the kernel part is controllable; its memory
// roofline is ~25-34us (>=143-210MB emb traffic + 10MB idx + 4MB out @6.3TB/s).

typedef float nfloat4 __attribute__((ext_vector_type(4)));

__global__ __launch_bounds__(256) void build_rowptr_kernel(
    const int* __restrict__ row_idx,
    int*       __restrict__ row_ptr,   // [num_sess+1]
    int nnz, int num_sess)
{
    int j = blockIdx.x * blockDim.x + threadIdx.x;
    if (j >= nnz) return;
    int r = row_idx[j];
    if (j == 0) {
        for (int s = 0; s <= r; ++s) row_ptr[s] = 0;        // lower_bound(s)=0 for s<=row[0]
    } else {
        int rp = row_idx[j - 1];
        for (int s = rp + 1; s <= r; ++s) row_ptr[s] = j;   // first idx >= s is j
    }
    if (j == nnz - 1) {
        for (int s = r + 1; s <= num_sess; ++s) row_ptr[s] = nnz;
    }
}

__global__ __launch_bounds__(256, 8) void wsum_sess_kernel(
    const int*    __restrict__ row_ptr,
    const int*    __restrict__ col_idx,
    const float*  __restrict__ data,
    const float4* __restrict__ emb,   // [ITEMS_NUM, 16] as float4
    float4*       __restrict__ out,   // [num_sess, 16] as float4
    int num_sess)
{
    const int wave = threadIdx.x >> 6;           // 0..3
    const int lane = threadIdx.x & 63;
    const int sess = (blockIdx.x << 2) + wave;   // one wave per session
    if (sess >= num_sess) return;

    const int start = row_ptr[sess];
    const int end   = row_ptr[sess + 1];

    const int r = lane >> 4;   // nnz chain within group-of-4
    const int c = lane & 15;   // float4 slot within the 64-float emb row

    float4 acc = make_float4(0.f, 0.f, 0.f, 0.f);

    int j0 = start;
    // 16 nnz per iteration: 4 independent gather chains in flight per lane
    for (; j0 + 16 <= end; j0 += 16) {
        int   c0 = col_idx[j0 + 0  + r];
        int   c1 = col_idx[j0 + 4  + r];
        int   c2 = col_idx[j0 + 8  + r];
        int   c3 = col_idx[j0 + 12 + r];
        float w0 = data[j0 + 0  + r];
        float w1 = data[j0 + 4  + r];
        float w2 = data[j0 + 8  + r];
        float w3 = data[j0 + 12 + r];
        float4 e0 = emb[((size_t)c0 << 4) + c];
        float4 e1 = emb[((size_t)c1 << 4) + c];
        float4 e2 = emb[((size_t)c2 << 4) + c];
        float4 e3 = emb[((size_t)c3 << 4) + c];
        acc.x += w0 * e0.x + w1 * e1.x + w2 * e2.x + w3 * e3.x;
        acc.y += w0 * e0.y + w1 * e1.y + w2 * e2.y + w3 * e3.y;
        acc.z += w0 * e0.z + w1 * e1.z + w2 * e2.z + w3 * e3.z;
        acc.w += w0 * e0.w + w1 * e1.w + w2 * e2.w + w3 * e3.w;
    }
    // tail: single masked pass of up to 16 nnz, 4 independent chains
    if (j0 < end) {
        #pragma unroll
        for (int k = 0; k < 4; ++k) {
            int   j     = j0 + (k << 2) + r;
            bool  valid = (j < end);
            int   col   = valid ? col_idx[j] : 0;
            float w     = valid ? data[j]    : 0.f;
            float4 e = emb[((size_t)col << 4) + c];
            acc.x += w * e.x;
            acc.y += w * e.y;
            acc.z += w * e.z;
            acc.w += w * e.w;
        }
    }

    // reduce the 4 chains (lanes differing in bits 4,5 hold the same dims)
    acc.x += __shfl_xor(acc.x, 16, 64);
    acc.y += __shfl_xor(acc.y, 16, 64);
    acc.z += __shfl_xor(acc.z, 16, 64);
    acc.w += __shfl_xor(acc.w, 16, 64);
    acc.x += __shfl_xor(acc.x, 32, 64);
    acc.y += __shfl_xor(acc.y, 32, 64);
    acc.z += __shfl_xor(acc.z, 32, 64);
    acc.w += __shfl_xor(acc.w, 32, 64);

    if (r == 0) {
        nfloat4 v = { acc.x, acc.y, acc.z, acc.w };
        __builtin_nontemporal_store(
            v, (nfloat4*)&out[((size_t)sess << 4) + c]);
    }
}

extern "C" void kernel_launch(void* const* d_in, const int* in_sizes, int n_in,
                              void* d_out, int out_size, void* d_ws, size_t ws_size,
                              hipStream_t stream) {
    const int*   row_idx = (const int*)  d_in[0];
    const int*   col_idx = (const int*)  d_in[1];
    const float* data    = (const float*)d_in[2];
    const float* emb     = (const float*)d_in[4];

    const int nnz      = in_sizes[0];
    const int num_sess = out_size / 64;   // EMB_DIM = 64

    int* row_ptr = (int*)d_ws;            // num_sess+1 ints (< 64KB+4)

    build_rowptr_kernel<<<(nnz + 255) / 256, 256, 0, stream>>>(
        row_idx, row_ptr, nnz, num_sess);

    const int blocks = (num_sess + 3) / 4;   // 4 waves/block, 1 session/wave
    wsum_sess_kernel<<<blocks, 256, 0, stream>>>(
        row_ptr, col_idx, data, (const float4*)emb, (float4*)d_out,
        num_sess);
}